// Round 6
// baseline (228.589 us; speedup 1.0000x reference)
//
#include <hip/hip_runtime.h>
#include <hip/hip_bf16.h>

typedef __bf16 bf16;
typedef __bf16 bf16x8 __attribute__((ext_vector_type(8)));
typedef __bf16 bf16x4 __attribute__((ext_vector_type(4)));
typedef float f32x4 __attribute__((ext_vector_type(4)));
typedef float f32x16 __attribute__((ext_vector_type(16)));

#define MFMA16(a, b, c) __builtin_amdgcn_mfma_f32_16x16x32_bf16((a), (b), (c), 0, 0, 0)
#define MFMA32(a, b, c) __builtin_amdgcn_mfma_f32_32x32x16_bf16((a), (b), (c), 0, 0, 0)

constexpr int S = 4096;
constexpr int E = 1024;
constexpr int H = 16;
constexpr int HD = 64;
constexpr float NEG = -1e30f;
// scores in log2 domain: fold 1/sqrt(64) * log2(e) into Q
constexpr float QSCALE = 0.125f * 1.44269504088896f;

__device__ inline f32x16 fzero16() {
  f32x16 z;
#pragma unroll
  for (int i = 0; i < 16; ++i) z[i] = 0.f;
  return z;
}

__device__ inline bf16x8 load_f32x8_as_bf16(const float* __restrict__ p) {
  float4 u0 = *reinterpret_cast<const float4*>(p);
  float4 u1 = *reinterpret_cast<const float4*>(p + 4);
  bf16x8 r;
  r[0] = (bf16)u0.x; r[1] = (bf16)u0.y; r[2] = (bf16)u0.z; r[3] = (bf16)u0.w;
  r[4] = (bf16)u1.x; r[5] = (bf16)u1.y; r[6] = (bf16)u1.z; r[7] = (bf16)u1.w;
  return r;
}

// ---------------- wo -> bf16 ----------------
__global__ __launch_bounds__(256) void cvt_wo_kernel(const float* __restrict__ wo,
                                                     bf16* __restrict__ wob) {
  int i = (blockIdx.x * 256 + threadIdx.x) * 4;
  float4 f = *reinterpret_cast<const float4*>(wo + i);
  bf16x4 b;
  b[0] = (bf16)f.x; b[1] = (bf16)f.y; b[2] = (bf16)f.z; b[3] = (bf16)f.w;
  *reinterpret_cast<bf16x4*>(wob + i) = b;
}

// ---------------- QKV projection ----------------
// Q pre-scaled by QSCALE; V written TRANSPOSED: vt[h][d][s]
__global__ __launch_bounds__(256) void qkv_kernel(
    const float* __restrict__ x, const float* __restrict__ wq,
    const float* __restrict__ wk, const float* __restrict__ wv,
    bf16* __restrict__ qb, bf16* __restrict__ kb, bf16* __restrict__ vt) {
  const int h = blockIdx.y;
  const int s0 = blockIdx.x * 64;
  const int w = threadIdx.x >> 6;
  const int l = threadIdx.x & 63;
  const int lg = l >> 4, lr = l & 15;

  bf16x8 af[2];
  {
    const float* xp = x + (size_t)(s0 + w * 16 + lr) * E + h * HD;
    af[0] = load_f32x8_as_bf16(xp + lg * 8);
    af[1] = load_f32x8_as_bf16(xp + 32 + lg * 8);
  }
  const float* Wsrc[3] = {wq + (size_t)h * HD * HD, wk + (size_t)h * HD * HD,
                          wv + (size_t)h * HD * HD};
#pragma unroll
  for (int pj = 0; pj < 3; ++pj) {
    f32x4 acc[4];
#pragma unroll
    for (int ot = 0; ot < 4; ++ot) acc[ot] = f32x4{0.f, 0.f, 0.f, 0.f};
#pragma unroll
    for (int ks = 0; ks < 2; ++ks) {
#pragma unroll
      for (int ot = 0; ot < 4; ++ot) {
        bf16x8 bfr = load_f32x8_as_bf16(Wsrc[pj] + (size_t)(ot * 16 + lr) * HD + ks * 32 + lg * 8);
        acc[ot] = MFMA16(af[ks], bfr, acc[ot]);
      }
    }
    if (pj == 2) {
      // V^T store: vt[(h*HD + o)][s]
#pragma unroll
      for (int ot = 0; ot < 4; ++ot) {
        bf16x4 b;
#pragma unroll
        for (int r = 0; r < 4; ++r) b[r] = (bf16)acc[ot][r];
        *reinterpret_cast<bf16x4*>(vt + (size_t)(h * HD + ot * 16 + lr) * S +
                                   s0 + w * 16 + lg * 4) = b;
      }
    } else {
      const float scale = (pj == 0) ? QSCALE : 1.0f;
      bf16* op = ((pj == 0) ? qb : kb) + (size_t)h * S * HD;
#pragma unroll
      for (int ot = 0; ot < 4; ++ot)
#pragma unroll
        for (int r = 0; r < 4; ++r)
          op[(size_t)(s0 + w * 16 + lg * 4 + r) * HD + ot * 16 + lr] =
              (bf16)(acc[ot][r] * scale);
    }
  }
}

// ---------------- causal flash attention: 8 waves, in-block kv-split ----------------
// XCD b&7 serves heads {2x,2x+1}; blocks b and b+256 carry complementary tiles
// (31-jj, jj) of the SAME head (constant per-CU work). 8 waves: waves 0-3 do
// EVEN kv-stages, waves 4-7 (same q-columns) do ODD stages; independent online
// softmax states merged exactly through LDS at the end. Doubles waves/SIMD.
__global__ __launch_bounds__(512, 4) void attn_kernel(
    const bf16* __restrict__ qb, const bf16* __restrict__ kb,
    const bf16* __restrict__ vt, bf16* __restrict__ ob) {
  __shared__ float accL[4][64][33];  // (l+r)%32 bank pattern: 2-way, free
  __shared__ float mlL[4][64][2];
  const int b = blockIdx.x;
  const int xcd = b & 7;
  const int idx = b >> 3;                    // 0..63
  const int head = 2 * xcd + (idx & 1);
  const int jj = (idx >> 1) & 15;
  const int qt = (idx < 32) ? (31 - jj) : jj;  // heavy round first
  const int tid = threadIdx.x;
  const int w = tid >> 6, l = tid & 63;
  const int w2 = w & 3, grp = w >> 2;        // grp 0: even stages, grp 1: odd
  const int lo = l & 31, hi = l >> 5;
  const int q0w = qt * 128 + w2 * 32;
  // stages this wave runs: st = 2*i + grp, i in [0, n)
  const int n = (grp == 0) ? (qt + 1) : (qt + (w2 >= 2 ? 1 : 0));

  bf16x8 qf[4];
  {
    const bf16* qp = qb + ((size_t)head * S + q0w + lo) * HD + hi * 8;
#pragma unroll
    for (int dt = 0; dt < 4; ++dt) qf[dt] = *reinterpret_cast<const bf16x8*>(qp + dt * 16);
  }
  const bf16* kbase = kb + (size_t)head * S * HD;
  const bf16* vbase = vt + (size_t)head * HD * S;

  f32x16 acc0 = fzero16(), acc1 = fzero16();
  float mrun = NEG, lsum = 0.f;

  for (int i = 0; i < n; ++i) {
    const int st = 2 * i + grp;
    const int kv0 = st * 64;
    // --- S^T[kv][q] = K @ Q ---
    f32x16 sv[2];
#pragma unroll
    for (int t = 0; t < 2; ++t) {
      f32x16 a = fzero16();
      const bf16* kp = kbase + (size_t)(kv0 + t * 32 + lo) * HD + hi * 8;
#pragma unroll
      for (int dt = 0; dt < 4; ++dt)
        a = MFMA32(*reinterpret_cast<const bf16x8*>(kp + dt * 16), qf[dt], a);
      sv[t] = a;
    }
    // --- issue V^T loads early (hidden under mask+softmax VALU) ---
    bf16x8 vf[2][2][2];
#pragma unroll
    for (int t = 0; t < 2; ++t)
#pragma unroll
      for (int dh = 0; dh < 2; ++dh) {
        const bf16* vp = vbase + (size_t)(dh * 32 + lo) * S + kv0 + t * 32 + hi * 8;
        vf[t][dh][0] = *reinterpret_cast<const bf16x8*>(vp);
        vf[t][dh][1] = *reinterpret_cast<const bf16x8*>(vp + 16);
      }
    // --- causal mask (near-diagonal stages only) ---
    if (kv0 + 63 > q0w) {
      const int q = q0w + lo;
#pragma unroll
      for (int t = 0; t < 2; ++t)
#pragma unroll
        for (int r = 0; r < 16; ++r) {
          int kv = kv0 + t * 32 + (r & 3) + 8 * (r >> 2) + 4 * hi;
          if (kv > q) sv[t][r] = NEG;
        }
    }
    // --- online softmax (log2 domain, defer-max thr=8) ---
    float tmax = NEG;
#pragma unroll
    for (int t = 0; t < 2; ++t)
#pragma unroll
      for (int r = 0; r < 16; ++r) tmax = fmaxf(tmax, sv[t][r]);
    if (!__all(tmax <= mrun + 8.f)) {
      float tm = fmaxf(tmax, __shfl_xor(tmax, 32));
      float mnew = fmaxf(mrun, tm);
      float alpha = exp2f(mrun - mnew);
      lsum *= alpha;
#pragma unroll
      for (int ii = 0; ii < 16; ++ii) { acc0[ii] *= alpha; acc1[ii] *= alpha; }
      mrun = mnew;
    }
    float psum = 0.f;
#pragma unroll
    for (int t = 0; t < 2; ++t)
#pragma unroll
      for (int r = 0; r < 16; ++r) {
        sv[t][r] = exp2f(sv[t][r] - mrun);
        psum += sv[t][r];
      }
    lsum += psum;
    // --- P -> bf16 pairs; half-wave exchange via permlane32_swap; PV ---
#pragma unroll
    for (int t = 0; t < 2; ++t) {
      unsigned wv[8];
#pragma unroll
      for (int ii = 0; ii < 8; ++ii) {
        union { unsigned u; bf16 h2[2]; } pu;
        pu.h2[0] = (bf16)sv[t][2 * ii];
        pu.h2[1] = (bf16)sv[t][2 * ii + 1];
        wv[ii] = pu.u;
      }
      asm("v_permlane32_swap_b32 %0, %1" : "+v"(wv[0]), "+v"(wv[2]));
      asm("v_permlane32_swap_b32 %0, %1" : "+v"(wv[1]), "+v"(wv[3]));
      asm("v_permlane32_swap_b32 %0, %1" : "+v"(wv[4]), "+v"(wv[6]));
      asm("v_permlane32_swap_b32 %0, %1" : "+v"(wv[5]), "+v"(wv[7]));
      union { bf16x8 v; unsigned u[4]; } B0, B1;
      B0.u[0] = wv[0]; B0.u[1] = wv[1]; B0.u[2] = wv[2]; B0.u[3] = wv[3];
      B1.u[0] = wv[4]; B1.u[1] = wv[5]; B1.u[2] = wv[6]; B1.u[3] = wv[7];
      acc0 = MFMA32(vf[t][0][0], B0.v, acc0);
      acc0 = MFMA32(vf[t][0][1], B1.v, acc0);
      acc1 = MFMA32(vf[t][1][0], B0.v, acc1);
      acc1 = MFMA32(vf[t][1][1], B1.v, acc1);
    }
  }

  // --- merge odd-group state into even-group through LDS ---
  if (grp == 1) {
    mlL[w2][l][0] = mrun;
    mlL[w2][l][1] = lsum;
#pragma unroll
    for (int r = 0; r < 16; ++r) {
      accL[w2][l][r] = acc0[r];
      accL[w2][l][16 + r] = acc1[r];
    }
  }
  __syncthreads();
  if (grp == 0) {
    const float mB = mlL[w2][l][0];
    const float lB = mlL[w2][l][1];
    const float M = fmaxf(mrun, mB);
    const float sA = exp2f(mrun - M);
    const float sB = exp2f(mB - M);
    float lc = lsum * sA + lB * sB;
#pragma unroll
    for (int r = 0; r < 16; ++r) {
      acc0[r] = acc0[r] * sA + accL[w2][l][r] * sB;
      acc1[r] = acc1[r] * sA + accL[w2][l][16 + r] * sB;
    }
    const float inv = 1.0f / (lc + __shfl_xor(lc, 32));
    bf16* obp = ob + (size_t)(q0w + lo) * E + head * HD;
#pragma unroll
    for (int dh = 0; dh < 2; ++dh)
#pragma unroll
      for (int g = 0; g < 4; ++g) {
        bf16x4 bb;
#pragma unroll
        for (int r = 0; r < 4; ++r)
          bb[r] = (bf16)(((dh == 0) ? acc0[g * 4 + r] : acc1[g * 4 + r]) * inv);
        *reinterpret_cast<bf16x4*>(obp + dh * 32 + 8 * g + 4 * hi) = bb;
      }
  }
}

// ---------------- output projection: out = attn @ wo^T (128x64 tiles) ----------------
__global__ __launch_bounds__(256) void out_gemm_kernel(
    const bf16* __restrict__ ob, const bf16* __restrict__ wob,
    float* __restrict__ out) {
  const int w = threadIdx.x >> 6, l = threadIdx.x & 63, lg = l >> 4, lr = l & 15;
  const int s0 = blockIdx.x * 128, e0 = blockIdx.y * 64;
  f32x4 acc[2][4];
#pragma unroll
  for (int i = 0; i < 2; ++i)
#pragma unroll
    for (int jj = 0; jj < 4; ++jj) acc[i][jj] = f32x4{0.f, 0.f, 0.f, 0.f};
  const bf16* ap0 = ob + (size_t)(s0 + w * 16 + lr) * E;
  const bf16* ap1 = ap0 + (size_t)64 * E;
#pragma unroll 2
  for (int k = 0; k < E; k += 32) {
    bf16x8 a0 = *reinterpret_cast<const bf16x8*>(ap0 + k + lg * 8);
    bf16x8 a1 = *reinterpret_cast<const bf16x8*>(ap1 + k + lg * 8);
#pragma unroll
    for (int ct = 0; ct < 4; ++ct) {
      bf16x8 bfr = *reinterpret_cast<const bf16x8*>(
          wob + (size_t)(e0 + ct * 16 + lr) * E + k + lg * 8);
      acc[0][ct] = MFMA16(a0, bfr, acc[0][ct]);
      acc[1][ct] = MFMA16(a1, bfr, acc[1][ct]);
    }
  }
#pragma unroll
  for (int half = 0; half < 2; ++half)
#pragma unroll
    for (int ct = 0; ct < 4; ++ct)
#pragma unroll
      for (int r = 0; r < 4; ++r)
        out[(size_t)(s0 + half * 64 + w * 16 + lg * 4 + r) * E + e0 + ct * 16 + lr] =
            acc[half][ct][r];
}

extern "C" void kernel_launch(void* const* d_in, const int* in_sizes, int n_in,
                              void* d_out, int out_size, void* d_ws, size_t ws_size,
                              hipStream_t stream) {
  const float* x  = (const float*)d_in[0];
  const float* wq = (const float*)d_in[1];
  const float* wk = (const float*)d_in[2];
  const float* wv = (const float*)d_in[3];
  const float* wo = (const float*)d_in[4];
  float* out = (float*)d_out;

  bf16* qb  = (bf16*)d_ws;                 // [H][S][HD]
  bf16* kb  = qb + (size_t)H * S * HD;     // [H][S][HD]
  bf16* vt  = kb + (size_t)H * S * HD;     // [H][HD][S]  (V transposed)
  bf16* ob  = vt + (size_t)H * S * HD;     // [S][E]
  bf16* wob = ob + (size_t)S * E;          // [E][E]

  cvt_wo_kernel<<<dim3(E * E / 1024), 256, 0, stream>>>(wo, wob);
  qkv_kernel<<<dim3(S / 64, H), 256, 0, stream>>>(x, wq, wk, wv, qb, kb, vt);
  attn_kernel<<<dim3(512), 512, 0, stream>>>(qb, kb, vt, ob);
  out_gemm_kernel<<<dim3(S / 128, E / 64), 256, 0, stream>>>(ob, wob, out);
}

// Round 7
// 210.094 us; speedup vs baseline: 1.0880x; 1.0880x over previous
//
#include <hip/hip_runtime.h>
#include <hip/hip_bf16.h>

typedef __bf16 bf16;
typedef __bf16 bf16x8 __attribute__((ext_vector_type(8)));
typedef __bf16 bf16x4 __attribute__((ext_vector_type(4)));
typedef float f32x4 __attribute__((ext_vector_type(4)));
typedef float f32x16 __attribute__((ext_vector_type(16)));

#define MFMA16(a, b, c) __builtin_amdgcn_mfma_f32_16x16x32_bf16((a), (b), (c), 0, 0, 0)
#define MFMA32(a, b, c) __builtin_amdgcn_mfma_f32_32x32x16_bf16((a), (b), (c), 0, 0, 0)

constexpr int S = 4096;
constexpr int E = 1024;
constexpr int H = 16;
constexpr int HD = 64;
constexpr float NEG = -1e30f;
// scores in log2 domain: fold 1/sqrt(64) * log2(e) into Q
constexpr float QSCALE = 0.125f * 1.44269504088896f;

template <int N> struct IC { static constexpr int value = N; };

__device__ inline f32x16 fzero16() {
  f32x16 z;
#pragma unroll
  for (int i = 0; i < 16; ++i) z[i] = 0.f;
  return z;
}

__device__ inline bf16x8 load_f32x8_as_bf16(const float* __restrict__ p) {
  float4 u0 = *reinterpret_cast<const float4*>(p);
  float4 u1 = *reinterpret_cast<const float4*>(p + 4);
  bf16x8 r;
  r[0] = (bf16)u0.x; r[1] = (bf16)u0.y; r[2] = (bf16)u0.z; r[3] = (bf16)u0.w;
  r[4] = (bf16)u1.x; r[5] = (bf16)u1.y; r[6] = (bf16)u1.z; r[7] = (bf16)u1.w;
  return r;
}

// ---------------- wo -> bf16 ----------------
__global__ __launch_bounds__(256) void cvt_wo_kernel(const float* __restrict__ wo,
                                                     bf16* __restrict__ wob) {
  int i = (blockIdx.x * 256 + threadIdx.x) * 4;
  float4 f = *reinterpret_cast<const float4*>(wo + i);
  bf16x4 b;
  b[0] = (bf16)f.x; b[1] = (bf16)f.y; b[2] = (bf16)f.z; b[3] = (bf16)f.w;
  *reinterpret_cast<bf16x4*>(wob + i) = b;
}

// ---------------- QKV projection ----------------
// Q pre-scaled by QSCALE; V written TRANSPOSED: vt[h][d][s]
__global__ __launch_bounds__(256) void qkv_kernel(
    const float* __restrict__ x, const float* __restrict__ wq,
    const float* __restrict__ wk, const float* __restrict__ wv,
    bf16* __restrict__ qb, bf16* __restrict__ kb, bf16* __restrict__ vt) {
  const int h = blockIdx.y;
  const int s0 = blockIdx.x * 64;
  const int w = threadIdx.x >> 6;
  const int l = threadIdx.x & 63;
  const int lg = l >> 4, lr = l & 15;

  bf16x8 af[2];
  {
    const float* xp = x + (size_t)(s0 + w * 16 + lr) * E + h * HD;
    af[0] = load_f32x8_as_bf16(xp + lg * 8);
    af[1] = load_f32x8_as_bf16(xp + 32 + lg * 8);
  }
  const float* Wsrc[3] = {wq + (size_t)h * HD * HD, wk + (size_t)h * HD * HD,
                          wv + (size_t)h * HD * HD};
#pragma unroll
  for (int pj = 0; pj < 3; ++pj) {
    f32x4 acc[4];
#pragma unroll
    for (int ot = 0; ot < 4; ++ot) acc[ot] = f32x4{0.f, 0.f, 0.f, 0.f};
#pragma unroll
    for (int ks = 0; ks < 2; ++ks) {
#pragma unroll
      for (int ot = 0; ot < 4; ++ot) {
        bf16x8 bfr = load_f32x8_as_bf16(Wsrc[pj] + (size_t)(ot * 16 + lr) * HD + ks * 32 + lg * 8);
        acc[ot] = MFMA16(af[ks], bfr, acc[ot]);
      }
    }
    if (pj == 2) {
      // V^T store: vt[(h*HD + o)][s]
#pragma unroll
      for (int ot = 0; ot < 4; ++ot) {
        bf16x4 b;
#pragma unroll
        for (int r = 0; r < 4; ++r) b[r] = (bf16)acc[ot][r];
        *reinterpret_cast<bf16x4*>(vt + (size_t)(h * HD + ot * 16 + lr) * S +
                                   s0 + w * 16 + lg * 4) = b;
      }
    } else {
      const float scale = (pj == 0) ? QSCALE : 1.0f;
      bf16* op = ((pj == 0) ? qb : kb) + (size_t)h * S * HD;
#pragma unroll
      for (int ot = 0; ot < 4; ++ot)
#pragma unroll
        for (int r = 0; r < 4; ++r)
          op[(size_t)(s0 + w * 16 + lg * 4 + r) * HD + ot * 16 + lr] =
              (bf16)(acc[ot][r] * scale);
    }
  }
}

// ---------------- causal flash attention: LDS-free, barrier-free, 128-kv stages ----------------
// XCD b&7 serves heads {2x,2x+1} (3 MB < 4 MB L2); blocks b and b+256 carry
// complementary tiles (31-jj, jj) of the SAME head -> constant per-CU work.
// 128-kv wide stages: 4 independent QK^T MFMA chains, ONE softmax pass per
// 128 kv, 4-way PV ILP. Swapped QK^T; in-register P via v_permlane32_swap_b32.
__global__ __launch_bounds__(256, 2) void attn_kernel(
    const bf16* __restrict__ qb, const bf16* __restrict__ kb,
    const bf16* __restrict__ vt, bf16* __restrict__ ob) {
  const int b = blockIdx.x;
  const int xcd = b & 7;
  const int idx = b >> 3;                    // 0..63
  const int head = 2 * xcd + (idx & 1);
  const int jj = (idx >> 1) & 15;
  const int qt = (idx < 32) ? (31 - jj) : jj;  // heavy round first; pair sums to 31
  const int tid = threadIdx.x;
  const int w = tid >> 6, l = tid & 63;
  const int lo = l & 31, hi = l >> 5;
  const int q0w = qt * 128 + w * 32;
  const int nstw = 2 * qt + 1 + (w >> 1);    // in 64-kv units; waves 0,1 skip masked last

  bf16x8 qf[4];
  {
    const bf16* qp = qb + ((size_t)head * S + q0w + lo) * HD + hi * 8;
#pragma unroll
    for (int dt = 0; dt < 4; ++dt) qf[dt] = *reinterpret_cast<const bf16x8*>(qp + dt * 16);
  }
  const bf16* kbase = kb + (size_t)head * S * HD;
  const bf16* vbase = vt + (size_t)head * HD * S;

  f32x16 acc0 = fzero16(), acc1 = fzero16();
  float mrun = NEG, lsum = 0.f;

  auto stage = [&](auto ntc, int kv0) {
    constexpr int NT = decltype(ntc)::value;  // 32-kv tiles this stage
    // --- S^T[kv][q] = K @ Q : NT independent 4-deep MFMA chains ---
    f32x16 sv[NT];
#pragma unroll
    for (int t = 0; t < NT; ++t) {
      f32x16 a = fzero16();
      const bf16* kp = kbase + (size_t)(kv0 + t * 32 + lo) * HD + hi * 8;
#pragma unroll
      for (int dt = 0; dt < 4; ++dt)
        a = MFMA32(*reinterpret_cast<const bf16x8*>(kp + dt * 16), qf[dt], a);
      sv[t] = a;
    }
    // --- issue V^T loads early (hidden under mask+softmax VALU) ---
    bf16x8 vf[NT][2][2];
#pragma unroll
    for (int t = 0; t < NT; ++t)
#pragma unroll
      for (int dh = 0; dh < 2; ++dh) {
        const bf16* vp = vbase + (size_t)(dh * 32 + lo) * S + kv0 + t * 32 + hi * 8;
        vf[t][dh][0] = *reinterpret_cast<const bf16x8*>(vp);
        vf[t][dh][1] = *reinterpret_cast<const bf16x8*>(vp + 16);
      }
    // --- causal mask (near-diagonal stages only) ---
    if (kv0 + NT * 32 - 1 > q0w) {
      const int q = q0w + lo;
#pragma unroll
      for (int t = 0; t < NT; ++t)
#pragma unroll
        for (int r = 0; r < 16; ++r) {
          int kv = kv0 + t * 32 + (r & 3) + 8 * (r >> 2) + 4 * hi;
          if (kv > q) sv[t][r] = NEG;
        }
    }
    // --- online softmax (log2 domain, defer-max thr=8), ONE pass per stage ---
    float tmax = NEG;
#pragma unroll
    for (int t = 0; t < NT; ++t)
#pragma unroll
      for (int r = 0; r < 16; ++r) tmax = fmaxf(tmax, sv[t][r]);
    if (!__all(tmax <= mrun + 8.f)) {
      float tm = fmaxf(tmax, __shfl_xor(tmax, 32));
      float mnew = fmaxf(mrun, tm);
      float alpha = exp2f(mrun - mnew);
      lsum *= alpha;
#pragma unroll
      for (int ii = 0; ii < 16; ++ii) { acc0[ii] *= alpha; acc1[ii] *= alpha; }
      mrun = mnew;
    }
    float psum = 0.f;
#pragma unroll
    for (int t = 0; t < NT; ++t)
#pragma unroll
      for (int r = 0; r < 16; ++r) {
        sv[t][r] = exp2f(sv[t][r] - mrun);
        psum += sv[t][r];
      }
    lsum += psum;
    // --- P -> bf16 pairs; half-wave exchange via permlane32_swap; PV ---
#pragma unroll
    for (int t = 0; t < NT; ++t) {
      unsigned wv[8];
#pragma unroll
      for (int ii = 0; ii < 8; ++ii) {
        union { unsigned u; bf16 h2[2]; } pu;
        pu.h2[0] = (bf16)sv[t][2 * ii];
        pu.h2[1] = (bf16)sv[t][2 * ii + 1];
        wv[ii] = pu.u;
      }
      asm("v_permlane32_swap_b32 %0, %1" : "+v"(wv[0]), "+v"(wv[2]));
      asm("v_permlane32_swap_b32 %0, %1" : "+v"(wv[1]), "+v"(wv[3]));
      asm("v_permlane32_swap_b32 %0, %1" : "+v"(wv[4]), "+v"(wv[6]));
      asm("v_permlane32_swap_b32 %0, %1" : "+v"(wv[5]), "+v"(wv[7]));
      union { bf16x8 v; unsigned u[4]; } B0, B1;
      B0.u[0] = wv[0]; B0.u[1] = wv[1]; B0.u[2] = wv[2]; B0.u[3] = wv[3];
      B1.u[0] = wv[4]; B1.u[1] = wv[5]; B1.u[2] = wv[6]; B1.u[3] = wv[7];
      acc0 = MFMA32(vf[t][0][0], B0.v, acc0);
      acc0 = MFMA32(vf[t][0][1], B1.v, acc0);
      acc1 = MFMA32(vf[t][1][0], B0.v, acc1);
      acc1 = MFMA32(vf[t][1][1], B1.v, acc1);
    }
  };

  int st = 0;
  for (; st + 1 < nstw; st += 2) stage(IC<4>{}, st * 64);  // 128-kv wide
  if (st < nstw) stage(IC<2>{}, st * 64);                  // 64-kv tail

  const float inv = 1.0f / (lsum + __shfl_xor(lsum, 32));
  bf16* obp = ob + (size_t)(q0w + lo) * E + head * HD;
#pragma unroll
  for (int dh = 0; dh < 2; ++dh)
#pragma unroll
    for (int g = 0; g < 4; ++g) {
      bf16x4 bb;
#pragma unroll
      for (int r = 0; r < 4; ++r)
        bb[r] = (bf16)(((dh == 0) ? acc0[g * 4 + r] : acc1[g * 4 + r]) * inv);
      *reinterpret_cast<bf16x4*>(obp + dh * 32 + 8 * g + 4 * hi) = bb;
    }
}

// ---------------- output projection: out = attn @ wo^T (128x64 tiles) ----------------
__global__ __launch_bounds__(256) void out_gemm_kernel(
    const bf16* __restrict__ ob, const bf16* __restrict__ wob,
    float* __restrict__ out) {
  const int w = threadIdx.x >> 6, l = threadIdx.x & 63, lg = l >> 4, lr = l & 15;
  const int s0 = blockIdx.x * 128, e0 = blockIdx.y * 64;
  f32x4 acc[2][4];
#pragma unroll
  for (int i = 0; i < 2; ++i)
#pragma unroll
    for (int jj = 0; jj < 4; ++jj) acc[i][jj] = f32x4{0.f, 0.f, 0.f, 0.f};
  const bf16* ap0 = ob + (size_t)(s0 + w * 16 + lr) * E;
  const bf16* ap1 = ap0 + (size_t)64 * E;
#pragma unroll 2
  for (int k = 0; k < E; k += 32) {
    bf16x8 a0 = *reinterpret_cast<const bf16x8*>(ap0 + k + lg * 8);
    bf16x8 a1 = *reinterpret_cast<const bf16x8*>(ap1 + k + lg * 8);
#pragma unroll
    for (int ct = 0; ct < 4; ++ct) {
      bf16x8 bfr = *reinterpret_cast<const bf16x8*>(
          wob + (size_t)(e0 + ct * 16 + lr) * E + k + lg * 8);
      acc[0][ct] = MFMA16(a0, bfr, acc[0][ct]);
      acc[1][ct] = MFMA16(a1, bfr, acc[1][ct]);
    }
  }
#pragma unroll
  for (int half = 0; half < 2; ++half)
#pragma unroll
    for (int ct = 0; ct < 4; ++ct)
#pragma unroll
      for (int r = 0; r < 4; ++r)
        out[(size_t)(s0 + half * 64 + w * 16 + lg * 4 + r) * E + e0 + ct * 16 + lr] =
            acc[half][ct][r];
}

extern "C" void kernel_launch(void* const* d_in, const int* in_sizes, int n_in,
                              void* d_out, int out_size, void* d_ws, size_t ws_size,
                              hipStream_t stream) {
  const float* x  = (const float*)d_in[0];
  const float* wq = (const float*)d_in[1];
  const float* wk = (const float*)d_in[2];
  const float* wv = (const float*)d_in[3];
  const float* wo = (const float*)d_in[4];
  float* out = (float*)d_out;

  bf16* qb  = (bf16*)d_ws;                 // [H][S][HD]
  bf16* kb  = qb + (size_t)H * S * HD;     // [H][S][HD]
  bf16* vt  = kb + (size_t)H * S * HD;     // [H][HD][S]  (V transposed)
  bf16* ob  = vt + (size_t)H * S * HD;     // [S][E]
  bf16* wob = ob + (size_t)S * E;          // [E][E]

  cvt_wo_kernel<<<dim3(E * E / 1024), 256, 0, stream>>>(wo, wob);
  qkv_kernel<<<dim3(S / 64, H), 256, 0, stream>>>(x, wq, wk, wv, qb, kb, vt);
  attn_kernel<<<dim3(512), 256, 0, stream>>>(qb, kb, vt, ob);
  out_gemm_kernel<<<dim3(S / 128, E / 64), 256, 0, stream>>>(ob, wob, out);
}

// Round 8
// 202.854 us; speedup vs baseline: 1.1269x; 1.0357x over previous
//
#include <hip/hip_runtime.h>
#include <hip/hip_bf16.h>

typedef __bf16 bf16;
typedef __bf16 bf16x8 __attribute__((ext_vector_type(8)));
typedef __bf16 bf16x4 __attribute__((ext_vector_type(4)));
typedef float f32x4 __attribute__((ext_vector_type(4)));
typedef float f32x16 __attribute__((ext_vector_type(16)));

#define MFMA16(a, b, c) __builtin_amdgcn_mfma_f32_16x16x32_bf16((a), (b), (c), 0, 0, 0)
#define MFMA32(a, b, c) __builtin_amdgcn_mfma_f32_32x32x16_bf16((a), (b), (c), 0, 0, 0)

constexpr int S = 4096;
constexpr int E = 1024;
constexpr int H = 16;
constexpr int HD = 64;
constexpr float NEG = -1e30f;
// scores in log2 domain: fold 1/sqrt(64) * log2(e) into Q
constexpr float QSCALE = 0.125f * 1.44269504088896f;

__device__ inline f32x16 fzero16() {
  f32x16 z;
#pragma unroll
  for (int i = 0; i < 16; ++i) z[i] = 0.f;
  return z;
}

__device__ inline bf16x8 load_f32x8_as_bf16(const float* __restrict__ p) {
  float4 u0 = *reinterpret_cast<const float4*>(p);
  float4 u1 = *reinterpret_cast<const float4*>(p + 4);
  bf16x8 r;
  r[0] = (bf16)u0.x; r[1] = (bf16)u0.y; r[2] = (bf16)u0.z; r[3] = (bf16)u0.w;
  r[4] = (bf16)u1.x; r[5] = (bf16)u1.y; r[6] = (bf16)u1.z; r[7] = (bf16)u1.w;
  return r;
}

// ---------------- wo -> bf16 ----------------
__global__ __launch_bounds__(256) void cvt_wo_kernel(const float* __restrict__ wo,
                                                     bf16* __restrict__ wob) {
  int i = (blockIdx.x * 256 + threadIdx.x) * 4;
  float4 f = *reinterpret_cast<const float4*>(wo + i);
  bf16x4 b;
  b[0] = (bf16)f.x; b[1] = (bf16)f.y; b[2] = (bf16)f.z; b[3] = (bf16)f.w;
  *reinterpret_cast<bf16x4*>(wob + i) = b;
}

// ---------------- QKV projection ----------------
// Q pre-scaled by QSCALE; V written TRANSPOSED: vt[h][d][s]
__global__ __launch_bounds__(256) void qkv_kernel(
    const float* __restrict__ x, const float* __restrict__ wq,
    const float* __restrict__ wk, const float* __restrict__ wv,
    bf16* __restrict__ qb, bf16* __restrict__ kb, bf16* __restrict__ vt) {
  const int h = blockIdx.y;
  const int s0 = blockIdx.x * 64;
  const int w = threadIdx.x >> 6;
  const int l = threadIdx.x & 63;
  const int lg = l >> 4, lr = l & 15;

  bf16x8 af[2];
  {
    const float* xp = x + (size_t)(s0 + w * 16 + lr) * E + h * HD;
    af[0] = load_f32x8_as_bf16(xp + lg * 8);
    af[1] = load_f32x8_as_bf16(xp + 32 + lg * 8);
  }
  const float* Wsrc[3] = {wq + (size_t)h * HD * HD, wk + (size_t)h * HD * HD,
                          wv + (size_t)h * HD * HD};
#pragma unroll
  for (int pj = 0; pj < 3; ++pj) {
    f32x4 acc[4];
#pragma unroll
    for (int ot = 0; ot < 4; ++ot) acc[ot] = f32x4{0.f, 0.f, 0.f, 0.f};
#pragma unroll
    for (int ks = 0; ks < 2; ++ks) {
#pragma unroll
      for (int ot = 0; ot < 4; ++ot) {
        bf16x8 bfr = load_f32x8_as_bf16(Wsrc[pj] + (size_t)(ot * 16 + lr) * HD + ks * 32 + lg * 8);
        acc[ot] = MFMA16(af[ks], bfr, acc[ot]);
      }
    }
    if (pj == 2) {
      // V^T store: vt[(h*HD + o)][s]
#pragma unroll
      for (int ot = 0; ot < 4; ++ot) {
        bf16x4 b;
#pragma unroll
        for (int r = 0; r < 4; ++r) b[r] = (bf16)acc[ot][r];
        *reinterpret_cast<bf16x4*>(vt + (size_t)(h * HD + ot * 16 + lr) * S +
                                   s0 + w * 16 + lg * 4) = b;
      }
    } else {
      const float scale = (pj == 0) ? QSCALE : 1.0f;
      bf16* op = ((pj == 0) ? qb : kb) + (size_t)h * S * HD;
#pragma unroll
      for (int ot = 0; ot < 4; ++ot)
#pragma unroll
        for (int r = 0; r < 4; ++r)
          op[(size_t)(s0 + w * 16 + lg * 4 + r) * HD + ot * 16 + lr] =
              (bf16)(acc[ot][r] * scale);
    }
  }
}

// ---------------- causal flash attention: LDS-free, barrier-free, K-prefetch ----------------
// XCD b&7 serves heads {2x,2x+1} (3 MB < 4 MB L2). qt map is balanced under
// BOTH candidate CU-pairing models: consecutive per-XCD blocks (2m,2m+1) AND
// (m,m+32) both sum to qt_a+qt_b=31. K(st+1) register-prefetched (ping-pong),
// issued AFTER V(st) loads so PV's waitcnt retires only V. Swapped QK^T;
// in-register P via v_permlane32_swap_b32.
__global__ __launch_bounds__(256, 2) void attn_kernel(
    const bf16* __restrict__ qb, const bf16* __restrict__ kb,
    const bf16* __restrict__ vt, bf16* __restrict__ ob) {
  const int b = blockIdx.x;
  const int xcd = b & 7;
  const int idx = b >> 3;                    // 0..63
  const int p = idx >> 1, hb = idx & 1;
  const int head = 2 * xcd + hb;
  const int qt = (p < 16) ? (hb ? p : 31 - p) : (hb ? 47 - p : p - 16);
  const int tid = threadIdx.x;
  const int w = tid >> 6, l = tid & 63;
  const int lo = l & 31, hi = l >> 5;
  const int q0w = qt * 128 + w * 32;
  const int nstw = 2 * qt + 1 + (w >> 1);    // waves 0,1 skip fully-masked last stage

  bf16x8 qf[4];
  {
    const bf16* qp = qb + ((size_t)head * S + q0w + lo) * HD + hi * 8;
#pragma unroll
    for (int dt = 0; dt < 4; ++dt) qf[dt] = *reinterpret_cast<const bf16x8*>(qp + dt * 16);
  }
  const bf16* kbase = kb + (size_t)head * S * HD;
  const bf16* vbase = vt + (size_t)head * HD * S;

  f32x16 acc0 = fzero16(), acc1 = fzero16();
  float mrun = NEG, lsum = 0.f;

  auto loadK = [&](int st, bf16x8 (&kf)[2][4]) {
    const bf16* kp = kbase + (size_t)(st * 64 + lo) * HD + hi * 8;
#pragma unroll
    for (int t = 0; t < 2; ++t)
#pragma unroll
      for (int dt = 0; dt < 4; ++dt)
        kf[t][dt] = *reinterpret_cast<const bf16x8*>(kp + t * 32 * HD + dt * 16);
  };

  auto stageBody = [&](int st, bf16x8 (&cur)[2][4], bf16x8 (&nxt)[2][4]) {
    const int kv0 = st * 64;
    // --- S^T[kv][q] = K @ Q (K already in registers) ---
    f32x16 sv[2];
#pragma unroll
    for (int t = 0; t < 2; ++t) {
      f32x16 a = fzero16();
#pragma unroll
      for (int dt = 0; dt < 4; ++dt) a = MFMA32(cur[t][dt], qf[dt], a);
      sv[t] = a;
    }
    // --- V(st) loads first, then K(st+1) prefetch: PV waits only on V ---
    bf16x8 vf[2][2][2];
#pragma unroll
    for (int t = 0; t < 2; ++t)
#pragma unroll
      for (int dh = 0; dh < 2; ++dh) {
        const bf16* vp = vbase + (size_t)(dh * 32 + lo) * S + kv0 + t * 32 + hi * 8;
        vf[t][dh][0] = *reinterpret_cast<const bf16x8*>(vp);
        vf[t][dh][1] = *reinterpret_cast<const bf16x8*>(vp + 16);
      }
    loadK(min(st + 1, nstw - 1), nxt);
    // --- causal mask (near-diagonal stages only) ---
    if (kv0 + 63 > q0w) {
      const int q = q0w + lo;
#pragma unroll
      for (int t = 0; t < 2; ++t)
#pragma unroll
        for (int r = 0; r < 16; ++r) {
          int kv = kv0 + t * 32 + (r & 3) + 8 * (r >> 2) + 4 * hi;
          if (kv > q) sv[t][r] = NEG;
        }
    }
    // --- online softmax (log2 domain, defer-max thr=8) ---
    float tmax = NEG;
#pragma unroll
    for (int t = 0; t < 2; ++t)
#pragma unroll
      for (int r = 0; r < 16; ++r) tmax = fmaxf(tmax, sv[t][r]);
    if (!__all(tmax <= mrun + 8.f)) {
      float tm = fmaxf(tmax, __shfl_xor(tmax, 32));
      float mnew = fmaxf(mrun, tm);
      float alpha = exp2f(mrun - mnew);
      lsum *= alpha;
#pragma unroll
      for (int ii = 0; ii < 16; ++ii) { acc0[ii] *= alpha; acc1[ii] *= alpha; }
      mrun = mnew;
    }
    float psum = 0.f;
#pragma unroll
    for (int t = 0; t < 2; ++t)
#pragma unroll
      for (int r = 0; r < 16; ++r) {
        sv[t][r] = exp2f(sv[t][r] - mrun);
        psum += sv[t][r];
      }
    lsum += psum;
    // --- P -> bf16 pairs; half-wave exchange via permlane32_swap; PV ---
#pragma unroll
    for (int t = 0; t < 2; ++t) {
      unsigned wv[8];
#pragma unroll
      for (int ii = 0; ii < 8; ++ii) {
        union { unsigned u; bf16 h2[2]; } pu;
        pu.h2[0] = (bf16)sv[t][2 * ii];
        pu.h2[1] = (bf16)sv[t][2 * ii + 1];
        wv[ii] = pu.u;
      }
      asm("v_permlane32_swap_b32 %0, %1" : "+v"(wv[0]), "+v"(wv[2]));
      asm("v_permlane32_swap_b32 %0, %1" : "+v"(wv[1]), "+v"(wv[3]));
      asm("v_permlane32_swap_b32 %0, %1" : "+v"(wv[4]), "+v"(wv[6]));
      asm("v_permlane32_swap_b32 %0, %1" : "+v"(wv[5]), "+v"(wv[7]));
      union { bf16x8 v; unsigned u[4]; } B0, B1;
      B0.u[0] = wv[0]; B0.u[1] = wv[1]; B0.u[2] = wv[2]; B0.u[3] = wv[3];
      B1.u[0] = wv[4]; B1.u[1] = wv[5]; B1.u[2] = wv[6]; B1.u[3] = wv[7];
      acc0 = MFMA32(vf[t][0][0], B0.v, acc0);
      acc0 = MFMA32(vf[t][0][1], B1.v, acc0);
      acc1 = MFMA32(vf[t][1][0], B0.v, acc1);
      acc1 = MFMA32(vf[t][1][1], B1.v, acc1);
    }
  };

  bf16x8 kA[2][4], kB[2][4];
  loadK(0, kA);
  int st = 0;
  for (; st + 1 < nstw; st += 2) {
    stageBody(st, kA, kB);
    stageBody(st + 1, kB, kA);
  }
  if (st < nstw) stageBody(st, kA, kB);

  const float inv = 1.0f / (lsum + __shfl_xor(lsum, 32));
  bf16* obp = ob + (size_t)(q0w + lo) * E + head * HD;
#pragma unroll
  for (int dh = 0; dh < 2; ++dh)
#pragma unroll
    for (int g = 0; g < 4; ++g) {
      bf16x4 bb;
#pragma unroll
      for (int r = 0; r < 4; ++r)
        bb[r] = (bf16)(((dh == 0) ? acc0[g * 4 + r] : acc1[g * 4 + r]) * inv);
      *reinterpret_cast<bf16x4*>(obp + dh * 32 + 8 * g + 4 * hi) = bb;
    }
}

// ---------------- output projection: out = attn @ wo^T (128x64 tiles) ----------------
__global__ __launch_bounds__(256) void out_gemm_kernel(
    const bf16* __restrict__ ob, const bf16* __restrict__ wob,
    float* __restrict__ out) {
  const int w = threadIdx.x >> 6, l = threadIdx.x & 63, lg = l >> 4, lr = l & 15;
  const int s0 = blockIdx.x * 128, e0 = blockIdx.y * 64;
  f32x4 acc[2][4];
#pragma unroll
  for (int i = 0; i < 2; ++i)
#pragma unroll
    for (int jj = 0; jj < 4; ++jj) acc[i][jj] = f32x4{0.f, 0.f, 0.f, 0.f};
  const bf16* ap0 = ob + (size_t)(s0 + w * 16 + lr) * E;
  const bf16* ap1 = ap0 + (size_t)64 * E;
#pragma unroll 2
  for (int k = 0; k < E; k += 32) {
    bf16x8 a0 = *reinterpret_cast<const bf16x8*>(ap0 + k + lg * 8);
    bf16x8 a1 = *reinterpret_cast<const bf16x8*>(ap1 + k + lg * 8);
#pragma unroll
    for (int ct = 0; ct < 4; ++ct) {
      bf16x8 bfr = *reinterpret_cast<const bf16x8*>(
          wob + (size_t)(e0 + ct * 16 + lr) * E + k + lg * 8);
      acc[0][ct] = MFMA16(a0, bfr, acc[0][ct]);
      acc[1][ct] = MFMA16(a1, bfr, acc[1][ct]);
    }
  }
#pragma unroll
  for (int half = 0; half < 2; ++half)
#pragma unroll
    for (int ct = 0; ct < 4; ++ct)
#pragma unroll
      for (int r = 0; r < 4; ++r)
        out[(size_t)(s0 + half * 64 + w * 16 + lg * 4 + r) * E + e0 + ct * 16 + lr] =
            acc[half][ct][r];
}

extern "C" void kernel_launch(void* const* d_in, const int* in_sizes, int n_in,
                              void* d_out, int out_size, void* d_ws, size_t ws_size,
                              hipStream_t stream) {
  const float* x  = (const float*)d_in[0];
  const float* wq = (const float*)d_in[1];
  const float* wk = (const float*)d_in[2];
  const float* wv = (const float*)d_in[3];
  const float* wo = (const float*)d_in[4];
  float* out = (float*)d_out;

  bf16* qb  = (bf16*)d_ws;                 // [H][S][HD]
  bf16* kb  = qb + (size_t)H * S * HD;     // [H][S][HD]
  bf16* vt  = kb + (size_t)H * S * HD;     // [H][HD][S]  (V transposed)
  bf16* ob  = vt + (size_t)H * S * HD;     // [S][E]
  bf16* wob = ob + (size_t)S * E;          // [E][E]

  cvt_wo_kernel<<<dim3(E * E / 1024), 256, 0, stream>>>(wo, wob);
  qkv_kernel<<<dim3(S / 64, H), 256, 0, stream>>>(x, wq, wk, wv, qb, kb, vt);
  attn_kernel<<<dim3(512), 256, 0, stream>>>(qb, kb, vt, ob);
  out_gemm_kernel<<<dim3(S / 128, E / 64), 256, 0, stream>>>(ob, wob, out);
}